// Round 1
// baseline (231.986 us; speedup 1.0000x reference)
//
#include <hip/hip_runtime.h>
#include <math.h>

// CPQuadRankLayer: per-n (N=2048) batched low-rank quad projections.
// B=16, IN=OUT=256, R=64, Q=4.
// out[b,n,o] = sum_r ( prod_q rmsnorm_r(x[b,n,q,:] @ Fq[n]^T) )[r] * gain[n] * Fo[n,r,o]
//              + mean_q x[b,n,q,o]
//
// One workgroup per n, 512 threads, ~148KB LDS, 1 WG/CU.
// Factor stream: 10 slabs of 32KB through a 2x32KB ping-pong LDS buffer via
// global_load_lds(16B), counted vmcnt (never 0 in the loop), raw s_barrier.

#define WAITVM(NLIT) asm volatile("s_waitcnt vmcnt(" #NLIT ") lgkmcnt(0)" ::: "memory")
#define LGKM0()      asm volatile("s_waitcnt lgkmcnt(0)" ::: "memory")
#define BARRIER()    __builtin_amdgcn_s_barrier()

__device__ __forceinline__ void g2l16(const float* g, float* l) {
  __builtin_amdgcn_global_load_lds(
      (const __attribute__((address_space(1))) void*)g,
      (__attribute__((address_space(3))) void*)l, 16, 0, 0);
}

#ifndef N_NODES
#define N_NODES 2048
#endif

__global__ __launch_bounds__(512, 2) void cpquad_kernel(
    const float* __restrict__ x,
    const float* __restrict__ ftl, const float* __restrict__ ftr,
    const float* __restrict__ fbl, const float* __restrict__ fbr,
    const float* __restrict__ fout, const float* __restrict__ gain,
    float* __restrict__ out) {

  // LDS layout
  alignas(16) __shared__ float s_xs[16384]; // [8 j][16 b * 4 q packed as c2=b*4+q][32 i]
  alignas(16) __shared__ float s_fb[16384]; // 2 bufs x 8192 floats:
                                            //  proj slab: [4 q][64 r][32 i] (i-slice j)
                                            //  fo half:   [32 r][256 o]
  alignas(16) __shared__ float s_ps[4096];  // [4 q][16 b][64 r]
  alignas(16) __shared__ float s_ms[1024];  // [16 b][64 r]
  __shared__ float s_rr[64];                // [4 q][16 b] : 1/rms

  const int t    = threadIdx.x;
  const int lane = t & 63;
  const int wid  = t >> 6;
  const int n    = blockIdx.x;

  const float gn = gain[n];

  // ---------- staging source addresses ----------
  // proj slab: 4 loads/wave; chunk c = wid*32 + k*8 + (lane>>3); q=c>>6, r=c&63
  // 16B slot within the 128B row-slice is XOR-swizzled by (r>>2)&7 so that the
  // compute-side ds_read_b128 spreads across bank clusters (source-side swizzle,
  // LDS dest stays linear as global_load_lds requires).
  const float* ssrc[4];
#pragma unroll
  for (int k = 0; k < 4; ++k) {
    const int c = wid*32 + k*8 + (lane >> 3);
    const int q = c >> 6, r = c & 63;
    const float* fq = (q == 0) ? ftl : ((q == 1) ? ftr : ((q == 2) ? fbl : fbr));
    ssrc[k] = fq + ((size_t)n*64 + r)*256 + (((lane & 7) ^ ((r >> 2) & 7)) << 2);
  }
  // x slice: 1 load/wave per slice j; chunk c2 = b*4+q
  const int c2 = wid*8 + (lane >> 3);
  const float* xsrc = x + (((size_t)(c2 >> 2)*N_NODES + n)*4 + (c2 & 3))*256 + ((lane & 7) << 2);
  // factor_out half: 4 loads/wave, fully linear
  const float* osrc = fout + (size_t)n*16384 + wid*1024 + (lane << 2);

  float* sdst = s_fb + wid*1024;  // + buf*8192 + k*256 (wave-uniform)
  float* xdst = s_xs + wid*256;   // + j*2048          (wave-uniform)

  // ---------- prologue: x slice 0 + proj slab 0 (buf 0) ----------
  g2l16(xsrc, xdst);
#pragma unroll
  for (int k = 0; k < 4; ++k) g2l16(ssrc[k], sdst + k*256);

  // ---------- projection phases (8 i-slices of 32) ----------
  float acc[4][8];
#pragma unroll
  for (int k = 0; k < 4; ++k)
#pragma unroll
    for (int b = 0; b < 8; ++b) acc[k][b] = 0.0f;

  const int iseg = t & 3;          // i sub-segment (8 i each)
  const int bh   = (t >> 2) & 1;   // b half (8 b each)
  const int rg   = (t >> 3) & 15;  // r group (4 r each)
  const int qq   = t >> 7;         // quadrant

#pragma unroll
  for (int p = 0; p < 8; ++p) {
    if (p < 7) {
      // issue next x slice + next proj slab into the other buffer
      g2l16(xsrc + (p+1)*32, xdst + (p+1)*2048);
#pragma unroll
      for (int k = 0; k < 4; ++k)
        g2l16(ssrc[k] + (p+1)*32, sdst + ((p+1)&1)*8192 + k*256);
      WAITVM(5);   // drain phase-p loads, keep the 5 just issued in flight
    } else {
      // issue factor_out half 0 into buf 0
#pragma unroll
      for (int k = 0; k < 4; ++k) g2l16(osrc + k*256, sdst + k*256);
      WAITVM(4);
    }
    BARRIER();

    const float* fqp = s_fb + (p & 1)*8192 + qq*2048 + rg*128; // rows rg*4..+3
    const float* xqp = s_xs + p*2048 + bh*1024 + qq*32;        // b = bh*8+bb
#pragma unroll
    for (int s = 0; s < 2; ++s) {
      const int sl = ((iseg*2 + s) ^ (rg & 7)) << 2;  // swizzled 16B slot
      float4 fv[4];
#pragma unroll
      for (int k = 0; k < 4; ++k) fv[k] = *(const float4*)(fqp + k*32 + sl);
      float4 xv[8];
#pragma unroll
      for (int b = 0; b < 8; ++b) xv[b] = *(const float4*)(xqp + b*128 + iseg*8 + s*4);
#pragma unroll
      for (int k = 0; k < 4; ++k)
#pragma unroll
        for (int b = 0; b < 8; ++b) {
          acc[k][b] = fmaf(fv[k].x, xv[b].x, acc[k][b]);
          acc[k][b] = fmaf(fv[k].y, xv[b].y, acc[k][b]);
          acc[k][b] = fmaf(fv[k].z, xv[b].z, acc[k][b]);
          acc[k][b] = fmaf(fv[k].w, xv[b].w, acc[k][b]);
        }
    }
    LGKM0(); BARRIER();
  }

  // issue factor_out half 1 into buf 1 (overlaps the serial section below)
#pragma unroll
  for (int k = 0; k < 4; ++k) g2l16(osrc + 8192 + k*256, sdst + 8192 + k*256);

  // ---------- reduce partial dots over the 4 isegs, write P ----------
#pragma unroll
  for (int k = 0; k < 4; ++k)
#pragma unroll
    for (int b = 0; b < 8; ++b) {
      float v = acc[k][b];
      v += __shfl_xor(v, 1);
      v += __shfl_xor(v, 2);
      acc[k][b] = v;
    }
#pragma unroll
  for (int k = 0; k < 4; ++k) {
    if (iseg == k) {   // constant index into acc (rule #20)
#pragma unroll
      for (int b = 0; b < 8; ++b)
        s_ps[qq*1024 + (bh*8 + b)*64 + rg*4 + k] = acc[k][b];
    }
  }
  LGKM0(); BARRIER();

  // ---------- RMS per (q,b) row: 8 rows per wave ----------
#pragma unroll
  for (int rr = 0; rr < 8; ++rr) {
    const int row = wid*8 + rr;
    const float v = s_ps[row*64 + lane];
    float ss = v * v;
#pragma unroll
    for (int d = 1; d < 64; d <<= 1) ss += __shfl_xor(ss, d);
    if (lane == 0) s_rr[row] = 1.0f / sqrtf(ss * (1.0f/64.0f) + 1e-6f);
  }
  LGKM0(); BARRIER();

  // ---------- merged[b][r] = gain * prod_q pnorm ----------
#pragma unroll
  for (int e0 = 0; e0 < 2; ++e0) {
    const int e = t + e0*512;
    const int b = e >> 6, r = e & 63;
    float m = gn;
#pragma unroll
    for (int q = 0; q < 4; ++q) m *= s_ps[q*1024 + b*64 + r] * s_rr[q*16 + b];
    s_ms[e] = m;
  }
  // one barrier serves: merged visibility + fo-half0 completion
  WAITVM(4); BARRIER();

  // ---------- out GEMM: thread = (2 b) x (4 o), o = lane*4 ----------
  float oa[2][4];
#pragma unroll
  for (int b = 0; b < 2; ++b) { oa[b][0] = oa[b][1] = oa[b][2] = oa[b][3] = 0.0f; }

#pragma unroll
  for (int h = 0; h < 2; ++h) {
    if (h == 1) { WAITVM(0); BARRIER(); }   // fo half 1 ready
    const float* fsp = s_fb + h*8192;       // [32 r][256 o]
#pragma unroll
    for (int rr = 0; rr < 32; ++rr) {
      const float4 f4 = *(const float4*)(fsp + rr*256 + (lane << 2));
      const float m0 = s_ms[(wid*2 + 0)*64 + h*32 + rr];
      const float m1 = s_ms[(wid*2 + 1)*64 + h*32 + rr];
      oa[0][0] = fmaf(m0, f4.x, oa[0][0]); oa[0][1] = fmaf(m0, f4.y, oa[0][1]);
      oa[0][2] = fmaf(m0, f4.z, oa[0][2]); oa[0][3] = fmaf(m0, f4.w, oa[0][3]);
      oa[1][0] = fmaf(m1, f4.x, oa[1][0]); oa[1][1] = fmaf(m1, f4.y, oa[1][1]);
      oa[1][2] = fmaf(m1, f4.z, oa[1][2]); oa[1][3] = fmaf(m1, f4.w, oa[1][3]);
    }
  }

  // ---------- residual (mean over q) + store ----------
#pragma unroll
  for (int bb = 0; bb < 2; ++bb) {
    const int b = wid*2 + bb;
    const float* xr = s_xs + (lane >> 3)*2048 + b*128 + ((lane & 7) << 2);
    float rx = 0.f, ry = 0.f, rz = 0.f, rw = 0.f;
#pragma unroll
    for (int q = 0; q < 4; ++q) {
      const float4 xv = *(const float4*)(xr + q*32);
      rx += xv.x; ry += xv.y; rz += xv.z; rw += xv.w;
    }
    float4 o4;
    o4.x = oa[bb][0] + 0.25f*rx;
    o4.y = oa[bb][1] + 0.25f*ry;
    o4.z = oa[bb][2] + 0.25f*rz;
    o4.w = oa[bb][3] + 0.25f*rw;
    *(float4*)(out + ((size_t)b*N_NODES + n)*256 + (lane << 2)) = o4;
  }
}

extern "C" void kernel_launch(void* const* d_in, const int* in_sizes, int n_in,
                              void* d_out, int out_size, void* d_ws, size_t ws_size,
                              hipStream_t stream) {
  const float* x   = (const float*)d_in[0];
  const float* ftl = (const float*)d_in[1];
  const float* ftr = (const float*)d_in[2];
  const float* fbl = (const float*)d_in[3];
  const float* fbr = (const float*)d_in[4];
  const float* fo  = (const float*)d_in[5];
  const float* gn  = (const float*)d_in[6];
  float* o = (float*)d_out;
  cpquad_kernel<<<dim3(N_NODES), dim3(512), 0, stream>>>(x, ftl, ftr, fbl, fbr, fo, gn, o);
}